// Round 9
// baseline (240.005 us; speedup 1.0000x reference)
//
#include <hip/hip_runtime.h>

typedef _Float16 f16;
typedef _Float16 f16x8 __attribute__((ext_vector_type(8)));
typedef _Float16 f16x4 __attribute__((ext_vector_type(4)));
typedef __fp16   h16x2 __attribute__((ext_vector_type(2)));
typedef float    f32x4 __attribute__((ext_vector_type(4)));

static constexpr int BATCH = 2, SEQ = 2048, DMODEL = 1024, HEADS = 16, DHEAD = 64;
static constexpr int MTOK = BATCH * SEQ;  // 4096 tokens
static constexpr float LOG2E = 1.44269504088896f;

// async global->LDS, 16B per lane, LDS dest = wave-uniform base + lane*16
#define GLOBAL_LOAD_LDS16(gptr, lptr)                                              \
  __builtin_amdgcn_global_load_lds(                                                \
      (const __attribute__((address_space(1))) void*)(gptr),                       \
      (__attribute__((address_space(3))) void*)(lptr), 16, 0, 0)

#define MFMA16(a, b, c) __builtin_amdgcn_mfma_f32_16x16x32_f16((a), (b), (c), 0, 0, 0)

// counted vmcnt wait (memory clobber pins surrounding ds/global ops)
#define WAITV_(N) asm volatile("s_waitcnt vmcnt(" #N ")" ::: "memory")
#define WAITV(N) WAITV_(N)

__device__ __forceinline__ float fexp2(float x) {
  float r;
  asm volatile("v_exp_f32 %0, %1" : "=v"(r) : "v"(x));
  return r;
}
__device__ __forceinline__ float m3(float a, float b, float c) {
  return fmaxf(fmaxf(a, b), c);  // clang fuses to v_max3_f32
}

// ---- 64x32 f16 image block (4KB = 2048 f16), paired-row XOR swizzle ----
__device__ __forceinline__ int imgAB(int mr, int kr) {
  int pr = mr >> 1;
  int jj = ((mr & 1) << 2) | (kr >> 3);
  int j = jj ^ (pr & 7);
  return pr * 64 + j * 8 + (kr & 7);
}
// K image: 32 s-rows x 64 dh, full-row swizzle
__device__ __forceinline__ int imgK(int sr, int dh) {
  return sr * 64 + (((dh >> 3) ^ (sr & 7)) << 3) + (dh & 7);
}

// ---------------- cast fp32 -> f16 image layout (z selects q/k/v) ----------------
__global__ __launch_bounds__(256) void cast3_kernel(
    const float* __restrict__ qs, const float* __restrict__ ks,
    const float* __restrict__ vs, f16* __restrict__ X0, f16* __restrict__ X1,
    f16* __restrict__ X2) {
  const int z = blockIdx.z;
  const float* src = z == 0 ? qs : z == 1 ? ks : vs;
  f16* dst = z == 0 ? X0 : z == 1 ? X1 : X2;
  int c = blockIdx.x * 256 + threadIdx.x;  // chunk id
  int blk = c >> 8, cb = c & 255;
  int pr = cb >> 3, j = cb & 7;
  int jj = j ^ (pr & 7);
  int mr = (pr << 1) | (jj >> 2);
  int kr = (jj & 3) << 3;
  int m = (blk >> 5) * 64 + mr;
  int k = (blk & 31) * 32 + kr;
  const float* s = src + (size_t)m * DMODEL + k;
  f32x4 a = *(const f32x4*)s, b = *(const f32x4*)(s + 4);
  f16x8 o;
  o[0] = (f16)a[0]; o[1] = (f16)a[1]; o[2] = (f16)a[2]; o[3] = (f16)a[3];
  o[4] = (f16)b[0]; o[5] = (f16)b[1]; o[6] = (f16)b[2]; o[7] = (f16)b[3];
  *(f16x8*)(dst + (size_t)c * 8) = o;
}

// ------------- weight transpose+cast to image: B[n][k] = w[k][n] -------------
__global__ __launch_bounds__(256) void transw_kernel(
    const float* __restrict__ w0, const float* __restrict__ w1,
    const float* __restrict__ w2, const float* __restrict__ w3,
    f16* __restrict__ Wimg) {
  const int z = blockIdx.z;
  const float* w = z == 0 ? w0 : z == 1 ? w1 : z == 2 ? w2 : w3;
  f16* t = Wimg + (size_t)z * DMODEL * DMODEL;
  __shared__ f16 lt[64][72];
  const int k0 = blockIdx.x * 64, n0 = blockIdx.y * 64;
  const int r = threadIdx.x >> 2, c0 = (threadIdx.x & 3) * 16;
  const float* src = w + (size_t)(k0 + r) * DMODEL + n0 + c0;
#pragma unroll
  for (int jx = 0; jx < 16; jx += 4) {
    f32x4 x = *(const f32x4*)(src + jx);
    lt[c0 + jx + 0][r] = (f16)x[0];
    lt[c0 + jx + 1][r] = (f16)x[1];
    lt[c0 + jx + 2][r] = (f16)x[2];
    lt[c0 + jx + 3][r] = (f16)x[3];
  }
  __syncthreads();
  const int n = n0 + r;
#pragma unroll
  for (int cw = 0; cw < 2; cw++) {
    int k = k0 + c0 + cw * 8;
    int blk = ((n >> 6) << 5) | (k >> 5);
    int off = blk * 2048 + imgAB(n & 63, k & 31);
    f16x8 v;
#pragma unroll
    for (int e = 0; e < 8; e++) v[e] = lt[r][c0 + cw * 8 + e];
    *(f16x8*)(t + off) = v;
  }
}

// ------- fused QKV projection GEMM: 128x128 tile, BK=32, 4 waves, z-fused ------
// TRIPLE-buffered LDS, prefetch distance 2, counted vmcnt + raw barriers.
// z=0: Qp linear f16 scaled by log2(e). z=1: Kp K-image. z=2: Vt V-image.
__global__ __launch_bounds__(256) void proj_kernel(
    const f16* __restrict__ Ximg, const f16* __restrict__ Wimg,
    const float* __restrict__ bq, const float* __restrict__ bk,
    const float* __restrict__ bv, f16* __restrict__ Qp, f16* __restrict__ Kp,
    f16* __restrict__ Vt, int zbase, size_t aStride) {
  __shared__ f16 As[3][4096];
  __shared__ f16 Bs[3][4096];
  const int z = zbase + blockIdx.z;
  const f16* A = Ximg + (size_t)blockIdx.z * aStride;
  const f16* Bw = Wimg + (size_t)z * DMODEL * DMODEL;
  int lin = blockIdx.x + (blockIdx.y << 3);
  int swz = ((lin & 7) << 5) + (lin >> 3);
  const int n0 = (swz & 7) * 128, m0 = (swz >> 3) * 128;
  const int tid = threadIdx.x, w = tid >> 6, l = tid & 63, q = l & 15, g = l >> 4;
  const int wr = w >> 1, wc = w & 1;
  const int KT = DMODEL >> 5;  // 32 k-tiles
  int aoff[4], boff[4];
#pragma unroll
  for (int mi = 0; mi < 4; mi++) {
    int mr = wr * 64 + mi * 16 + q;
    aoff[mi] = ((mr >> 6) << 11) + imgAB(mr & 63, g * 8);
  }
#pragma unroll
  for (int ni = 0; ni < 4; ni++) {
    int nr = wc * 64 + ni * 16 + q;
    boff[ni] = ((nr >> 6) << 11) + imgAB(nr & 63, g * 8);
  }
  f32x4 acc[4][4] = {};
  f16 *pa0 = &As[0][0], *pa1 = &As[1][0], *pa2 = &As[2][0];
  f16 *pb0 = &Bs[0][0], *pb1 = &Bs[1][0], *pb2 = &Bs[2][0];

#define PROJ_STAGE(abuf, bbuf, t)                                                  \
  {                                                                                \
    _Pragma("unroll")                                                              \
    for (int i = 0; i < 2; i++) {                                                  \
      int c = w * 2 + i;                                                           \
      size_t ga = (size_t)(((m0 >> 6) + (c >> 2)) * KT + (t)) * 2048 +             \
                  (c & 3) * 512 + l * 8;                                           \
      GLOBAL_LOAD_LDS16(A + ga, (char*)&(abuf)[c * 512]);                          \
      size_t gb = (size_t)(((n0 >> 6) + (c >> 2)) * KT + (t)) * 2048 +             \
                  (c & 3) * 512 + l * 8;                                           \
      GLOBAL_LOAD_LDS16(Bw + gb, (char*)&(bbuf)[c * 512]);                         \
    }                                                                              \
  }

  PROJ_STAGE(pa0, pb0, 0);
  PROJ_STAGE(pa1, pb1, 1);
  for (int t = 0; t < KT; t++) {
    if (t + 2 < KT) {
      PROJ_STAGE(pa2, pb2, t + 2);
      WAITV(8);                       // tiles t+1,t+2 in flight; tile t landed
    } else if (t + 1 < KT) {
      WAITV(4);
    } else {
      WAITV(0);
    }
    __builtin_amdgcn_s_barrier();
    f16x8 af[4], bf[4];
#pragma unroll
    for (int mi = 0; mi < 4; mi++) af[mi] = *(const f16x8*)&pa0[aoff[mi]];
#pragma unroll
    for (int ni = 0; ni < 4; ni++) bf[ni] = *(const f16x8*)&pb0[boff[ni]];
#pragma unroll
    for (int mi = 0; mi < 4; mi++)
#pragma unroll
      for (int ni = 0; ni < 4; ni++)
        acc[mi][ni] = MFMA16(af[mi], bf[ni], acc[mi][ni]);
    __builtin_amdgcn_s_barrier();
    f16* tA = pa0; pa0 = pa1; pa1 = pa2; pa2 = tA;
    f16* tB = pb0; pb0 = pb1; pb1 = pb2; pb2 = tB;
  }
  const float* bias = z == 0 ? bq : (z == 1 ? bk : bv);
#pragma unroll
  for (int mi = 0; mi < 4; mi++)
#pragma unroll
    for (int ni = 0; ni < 4; ni++) {
      const int col = n0 + wc * 64 + ni * 16 + q;
      const float bvl = bias[col];
      const int row0 = m0 + wr * 64 + mi * 16 + g * 4;
      if (z == 0) {
#pragma unroll
        for (int r = 0; r < 4; r++)
          Qp[(size_t)(row0 + r) * DMODEL + col] = (f16)((acc[mi][ni][r] + bvl) * LOG2E);
      } else if (z == 1) {
        const int h = col >> 6, dh = col & 63;
#pragma unroll
        for (int r = 0; r < 4; r++) {
          const int row = row0 + r, s = row & (SEQ - 1);
          Kp[(size_t)(((row >> 11) * HEADS + h) * 64 + (s >> 5)) * 2048 + imgK(s & 31, dh)] =
              (f16)(acc[mi][ni][r] + bvl);
        }
      } else {
        const int h = col >> 6, dh = col & 63;
        const int s0 = row0 & (SEQ - 1);
        f16* dst = Vt + (size_t)(((row0 >> 11) * HEADS + h) * 64 + (s0 >> 5)) * 2048 +
                   imgAB(dh, s0 & 31);
        f16x4 ov;
        ov[0] = (f16)(acc[mi][ni][0] + bvl); ov[1] = (f16)(acc[mi][ni][1] + bvl);
        ov[2] = (f16)(acc[mi][ni][2] + bvl); ov[3] = (f16)(acc[mi][ni][3] + bvl);
        *(f16x4*)dst = ov;
      }
    }
}

// ---------------- flash attention (scores pre-scaled by log2e) ----------------
// 2 waves x 32 q-rows (2 independent Q-fragments each), KVBLK=64, dbuf LDS,
// counted vmcnt + raw barriers, setprio on MFMA. Row-sums l accumulated by an
// extra MFMA with a ones A-operand; lAa[0] is already the COMPLETE row sum
// (MFMA reduces over the full k dim) -> no cross-lane reduction at finalize.
// Output written in out-GEMM image layout with the reference's transpose-bug
// scramble: b'=h>>3, s'=((2h+b)&15)*128+s/16, d'=(s%16)*64+dh.
__global__ __launch_bounds__(128, 2) void attn_kernel(
    const f16* __restrict__ Qp, const f16* __restrict__ Kimg,
    const f16* __restrict__ Vimg, f16* __restrict__ Simg) {
  __shared__ f16 Klds[2][2][2048];      // 16KB
  __shared__ f16 Vlds[2][2][2048];      // 16KB
  __shared__ f16 Plds[2][2][2][512];    // [wave][frag][half]  8KB
  const int tid = threadIdx.x, w = tid >> 6, l = tid & 63, q = l & 15, g = l >> 4;
  const int lin = blockIdx.x;
  const int swz = ((lin & 7) << 7) + (lin >> 3);  // XCD chunking: 4 heads/XCD
  const int qb = swz & 31, bh = swz >> 5;
  const int b = bh >> 4, h = bh & 15;
  const int q0 = qb * 64 + w * 32;

  const f16* qrowA = Qp + (size_t)(b * SEQ + q0 + q) * DMODEL + h * 64;
  const f16x8 qA0 = *(const f16x8*)(qrowA + g * 8);
  const f16x8 qA1 = *(const f16x8*)(qrowA + 32 + g * 8);
  const f16* qrowB = qrowA + (size_t)16 * DMODEL;
  const f16x8 qB0 = *(const f16x8*)(qrowB + g * 8);
  const f16x8 qB1 = *(const f16x8*)(qrowB + 32 + g * 8);

  const f16* kt_base = Kimg + (size_t)(bh * 64) * 2048;
  const f16* vt_base = Vimg + (size_t)(bh * 64) * 2048;

  int koff[4][2];
#pragma unroll
  for (int fn = 0; fn < 4; fn++)
#pragma unroll
    for (int hf = 0; hf < 2; hf++)
      koff[fn][hf] = (fn >> 1) * 2048 + imgK((fn & 1) * 16 + q, hf * 32 + g * 8);
  int voff[4];
#pragma unroll
  for (int fo = 0; fo < 4; fo++) voff[fo] = imgAB(fo * 16 + q, g * 8);
  const int poff = imgAB(q, g * 8);
  int pwoff[2];
  {
    const int pr = q >> 1;
#pragma unroll
    for (int fn = 0; fn < 2; fn++) {
      int jj = ((q & 1) << 2) | (fn * 2 + (g >> 1));
      pwoff[fn] = pr * 64 + ((jj ^ (pr & 7)) << 3) + (g & 1) * 4;
    }
  }
  f16* PwA = &Plds[w][0][0][0];
  f16* PwB = &Plds[w][1][0][0];
  float mA = -1.0e30f, mB = -1.0e30f;
  f32x4 oA[4] = {}, oB[4] = {};
  f32x4 lAa = {}, lBa = {};           // MFMA row-sum accumulators (rows equal)
  f16x8 ones;
#pragma unroll
  for (int e = 0; e < 8; e++) ones[e] = (f16)1.0f;

  // wave 0 stages the 8KB K tile, wave 1 the 8KB V tile (8 x 1KB issues each)
#define ATTN_STAGE(bb, t)                                                          \
  {                                                                                \
    const f16* sb_ = (w == 0) ? (kt_base + (size_t)(2 * (t)) * 2048)               \
                              : (vt_base + (size_t)(2 * (t)) * 2048);              \
    f16* db_ = (w == 0) ? &Klds[bb][0][0] : &Vlds[bb][0][0];                       \
    _Pragma("unroll")                                                              \
    for (int j_ = 0; j_ < 8; j_++)                                                 \
      GLOBAL_LOAD_LDS16(sb_ + j_ * 512 + l * 8, (char*)(db_ + j_ * 512));          \
  }

#define SOFTMAX_FRAG(s, m_st, l_acc, o, PbF)                                       \
  {                                                                                \
    float lm = fmaxf(m3(m3(s[0][0], s[0][1], s[0][2]),                             \
                        m3(s[0][3], s[1][0], s[1][1]),                             \
                        m3(s[1][2], s[1][3], s[2][0])),                            \
                     m3(m3(s[2][1], s[2][2], s[2][3]),                             \
                        m3(s[3][0], s[3][1], s[3][2]), s[3][3]));                  \
    if (!__all(lm <= m_st + 8.f)) {                                                \
      float mx = fmaxf(lm, __shfl_xor(lm, 16, 64));                                \
      mx = fmaxf(mx, __shfl_xor(mx, 32, 64));                                      \
      const float mnew = fmaxf(m_st, mx);                                          \
      const float sc = fexp2(m_st - mnew);                                         \
      m_st = mnew;                                                                 \
      l_acc[0] *= sc; l_acc[1] *= sc; l_acc[2] *= sc; l_acc[3] *= sc;              \
      _Pragma("unroll")                                                            \
      for (int fo_ = 0; fo_ < 4; fo_++) {                                          \
        o[fo_][0] *= sc; o[fo_][1] *= sc; o[fo_][2] *= sc; o[fo_][3] *= sc;        \
      }                                                                            \
    }                                                                              \
    _Pragma("unroll")                                                              \
    for (int fn_ = 0; fn_ < 4; fn_++) {                                            \
      float e0 = fexp2(s[fn_][0] - m_st);                                          \
      float e1 = fexp2(s[fn_][1] - m_st);                                          \
      float e2 = fexp2(s[fn_][2] - m_st);                                          \
      float e3 = fexp2(s[fn_][3] - m_st);                                          \
      union { f16x4 v4; h16x2 h2[2]; } pu_;                                        \
      pu_.h2[0] = __builtin_amdgcn_cvt_pkrtz(e0, e1);                              \
      pu_.h2[1] = __builtin_amdgcn_cvt_pkrtz(e2, e3);                              \
      *(f16x4*)((PbF) + (fn_ >> 1) * 512 + pwoff[fn_ & 1]) = pu_.v4;               \
    }                                                                              \
  }

  ATTN_STAGE(0, 0);
  for (int t = 0; t < 32; t++) {
    const int bb = t & 1;
    if (t < 31) {
      ATTN_STAGE(bb ^ 1, t + 1);
      WAITV(8);
    } else {
      WAITV(0);
    }
    __builtin_amdgcn_s_barrier();
    const f16* Kb = &Klds[bb][0][0];
    f16x8 kf[4][2];
#pragma unroll
    for (int fn = 0; fn < 4; fn++) {
      kf[fn][0] = *(const f16x8*)(Kb + koff[fn][0]);
      kf[fn][1] = *(const f16x8*)(Kb + koff[fn][1]);
    }
    f32x4 sA[4], sB[4];
    __builtin_amdgcn_s_setprio(1);
#pragma unroll
    for (int fn = 0; fn < 4; fn++) {
      f32x4 z0 = {};
      z0 = MFMA16(kf[fn][0], qA0, z0);
      z0 = MFMA16(kf[fn][1], qA1, z0);
      sA[fn] = z0;
      f32x4 z1 = {};
      z1 = MFMA16(kf[fn][0], qB0, z1);
      z1 = MFMA16(kf[fn][1], qB1, z1);
      sB[fn] = z1;
    }
    __builtin_amdgcn_s_setprio(0);
    SOFTMAX_FRAG(sA, mA, lAa, oA, PwA);
    SOFTMAX_FRAG(sB, mB, lBa, oB, PwB);
    const f16x8 pA0 = *(const f16x8*)(PwA + poff);
    const f16x8 pA1 = *(const f16x8*)(PwA + 512 + poff);
    const f16x8 pB0 = *(const f16x8*)(PwB + poff);
    const f16x8 pB1 = *(const f16x8*)(PwB + 512 + poff);
    const f16* Vb = &Vlds[bb][0][0];
    f16x8 vf[4][2];
#pragma unroll
    for (int fo = 0; fo < 4; fo++) {
      vf[fo][0] = *(const f16x8*)(Vb + voff[fo]);
      vf[fo][1] = *(const f16x8*)(Vb + 2048 + voff[fo]);
    }
    __builtin_amdgcn_s_setprio(1);
#pragma unroll
    for (int fo = 0; fo < 4; fo++) {
      oA[fo] = MFMA16(vf[fo][0], pA0, oA[fo]);
      oA[fo] = MFMA16(vf[fo][1], pA1, oA[fo]);
      oB[fo] = MFMA16(vf[fo][0], pB0, oB[fo]);
      oB[fo] = MFMA16(vf[fo][1], pB1, oB[fo]);
    }
    // row sums: l += ones . P  (MFMA reduces over full k dim -> complete sum)
    lAa = MFMA16(ones, pA0, lAa);
    lAa = MFMA16(ones, pA1, lAa);
    lBa = MFMA16(ones, pB0, lBa);
    lBa = MFMA16(ones, pB1, lBa);
    __builtin_amdgcn_s_setprio(0);
    __builtin_amdgcn_s_barrier();
  }
  // --- finalize + scrambled store; lAa[0]/lBa[0] are already complete sums ---
  const float invA = 1.f / lAa[0], invB = 1.f / lBa[0];
  const int m16 = (2 * h + b) & 15, bp = h >> 3;
#pragma unroll
  for (int half = 0; half < 2; half++) {
    const int s = q0 + half * 16 + q;
    const int tp = bp * SEQ + m16 * 128 + (s >> 4);
    const float inv = half ? invB : invA;
    const f32x4* o = half ? oB : oA;
#pragma unroll
    for (int fo = 0; fo < 4; fo++) {
      const int d0 = (s & 15) * 64 + fo * 16 + g * 4;
      f16* dst = Simg + (size_t)(((tp >> 6) << 5) | (d0 >> 5)) * 2048 + imgAB(tp & 63, d0 & 31);
      f16x4 ov;
      ov[0] = (f16)(o[fo][0] * inv); ov[1] = (f16)(o[fo][1] * inv);
      ov[2] = (f16)(o[fo][2] * inv); ov[3] = (f16)(o[fo][3] * inv);
      *(f16x4*)dst = ov;
    }
  }
}

// ------------- output GEMM: 128x64 tile, BK=32, triple-buffer prefetch-2 -------------
__global__ __launch_bounds__(256) void ogemm_kernel(
    const f16* __restrict__ Aimg, const f16* __restrict__ Bimg,
    const float* __restrict__ bias, float* __restrict__ out) {
  __shared__ f16 As[3][4096];
  __shared__ f16 Bs[3][2048];
  int lin = blockIdx.x + (blockIdx.y << 4);
  int swz = ((lin & 7) << 6) + (lin >> 3);
  const int n0 = (swz & 15) * 64, m0 = (swz >> 4) * 128;
  const int tid = threadIdx.x, w = tid >> 6, l = tid & 63, q = l & 15, g = l >> 4;
  const int wr = w >> 1, wc = w & 1;
  int aoff[4], boff[2];
#pragma unroll
  for (int mi = 0; mi < 4; mi++) {
    int mr = wr * 64 + mi * 16 + q;
    aoff[mi] = ((mr >> 6) << 11) + imgAB(mr & 63, g * 8);
  }
#pragma unroll
  for (int ni = 0; ni < 2; ni++) boff[ni] = imgAB(wc * 32 + ni * 16 + q, g * 8);
  f32x4 acc[4][2] = {};
  f16 *pa0 = &As[0][0], *pa1 = &As[1][0], *pa2 = &As[2][0];
  f16 *pb0 = &Bs[0][0], *pb1 = &Bs[1][0], *pb2 = &Bs[2][0];

#define OG_STAGE(abuf, bbuf, t)                                                    \
  {                                                                                \
    _Pragma("unroll")                                                              \
    for (int i = 0; i < 2; i++) {                                                  \
      int c = w * 2 + i;                                                           \
      size_t ga = (size_t)(((m0 >> 6) + (c >> 2)) * 32 + (t)) * 2048 +             \
                  (c & 3) * 512 + l * 8;                                           \
      GLOBAL_LOAD_LDS16(Aimg + ga, (char*)&(abuf)[c * 512]);                       \
    }                                                                              \
    size_t gb = (size_t)((n0 >> 6) * 32 + (t)) * 2048 + w * 512 + l * 8;           \
    GLOBAL_LOAD_LDS16(Bimg + gb, (char*)&(bbuf)[w * 512]);                         \
  }

  OG_STAGE(pa0, pb0, 0);
  OG_STAGE(pa1, pb1, 1);
  for (int t = 0; t < 32; t++) {
    if (t + 2 < 32) {
      OG_STAGE(pa2, pb2, t + 2);
      WAITV(6);
    } else if (t + 1 < 32) {
      WAITV(3);
    } else {
      WAITV(0);
    }
    __builtin_amdgcn_s_barrier();
    f16x8 af[4], bf[2];
#pragma unroll
    for (int mi = 0; mi < 4; mi++) af[mi] = *(const f16x8*)&pa0[aoff[mi]];
#pragma unroll
    for (int ni = 0; ni < 2; ni++) bf[ni] = *(const f16x8*)&pb0[boff[ni]];
#pragma unroll
    for (int mi = 0; mi < 4; mi++)
#pragma unroll
      for (int ni = 0; ni < 2; ni++)
        acc[mi][ni] = MFMA16(af[mi], bf[ni], acc[mi][ni]);
    __builtin_amdgcn_s_barrier();
    f16* tA = pa0; pa0 = pa1; pa1 = pa2; pa2 = tA;
    f16* tB = pb0; pb0 = pb1; pb1 = pb2; pb2 = tB;
  }
#pragma unroll
  for (int mi = 0; mi < 4; mi++)
#pragma unroll
    for (int ni = 0; ni < 2; ni++) {
      const int col = n0 + wc * 32 + ni * 16 + q;
      const float bvl = bias[col];
      const int row0 = m0 + wr * 64 + mi * 16 + g * 4;
#pragma unroll
      for (int r = 0; r < 4; r++)
        out[(size_t)(row0 + r) * DMODEL + col] = acc[mi][ni][r] + bvl;
    }
}

extern "C" void kernel_launch(void* const* d_in, const int* in_sizes, int n_in,
                              void* d_out, int out_size, void* d_ws, size_t ws_size,
                              hipStream_t stream) {
  const float* q  = (const float*)d_in[0];
  const float* k  = (const float*)d_in[1];
  const float* v  = (const float*)d_in[2];
  const float* wq = (const float*)d_in[3];
  const float* bq = (const float*)d_in[4];
  const float* wk = (const float*)d_in[5];
  const float* bk = (const float*)d_in[6];
  const float* wv = (const float*)d_in[7];
  const float* bv = (const float*)d_in[8];
  const float* wo = (const float*)d_in[9];
  const float* bo = (const float*)d_in[10];

  const size_t XSZ = (size_t)MTOK * DMODEL;  // 4M f16 = 8MB
  f16* ws = (f16*)d_ws;
  const bool fused = ws_size >= (56ull << 20);

  f16 *X0, *X1, *X2, *Qp, *Kp, *Vt, *Wimg, *scr;
  if (fused) {
    X0 = ws; X1 = ws + XSZ; X2 = ws + 2 * XSZ;
    Qp = ws + 3 * XSZ; Kp = ws + 4 * XSZ; Vt = ws + 5 * XSZ;
    Wimg = ws + 6 * XSZ;
    scr = X0;
  } else {
    X0 = X1 = X2 = ws;
    Qp = ws + XSZ; Kp = ws + 2 * XSZ; Vt = ws + 3 * XSZ;
    Wimg = ws + 4 * XSZ;
    scr = X0;
  }

  dim3 blk(256), blk128(128);
  dim3 gT(16, 16, 4);
  dim3 gA(1024);
  dim3 gO(16, 32);

  transw_kernel<<<gT, blk, 0, stream>>>(wq, wk, wv, wo, Wimg);

  if (fused) {
    cast3_kernel<<<dim3(2048, 1, 3), blk, 0, stream>>>(q, k, v, X0, X1, X2);
    proj_kernel<<<dim3(8, 32, 3), blk, 0, stream>>>(X0, Wimg, bq, bk, bv, Qp, Kp, Vt, 0, XSZ);
  } else {
    cast3_kernel<<<dim3(2048, 1, 1), blk, 0, stream>>>(q, q, q, X0, X0, X0);
    proj_kernel<<<dim3(8, 32, 1), blk, 0, stream>>>(X0, Wimg, bq, bk, bv, Qp, Kp, Vt, 0, 0);
    cast3_kernel<<<dim3(2048, 1, 1), blk, 0, stream>>>(k, k, k, X0, X0, X0);
    proj_kernel<<<dim3(8, 32, 1), blk, 0, stream>>>(X0, Wimg, bq, bk, bv, Qp, Kp, Vt, 1, 0);
    cast3_kernel<<<dim3(2048, 1, 1), blk, 0, stream>>>(v, v, v, X0, X0, X0);
    proj_kernel<<<dim3(8, 32, 1), blk, 0, stream>>>(X0, Wimg, bq, bk, bv, Qp, Kp, Vt, 2, 0);
  }

  attn_kernel<<<gA, blk128, 0, stream>>>(Qp, Kp, Vt, scr);
  ogemm_kernel<<<gO, blk, 0, stream>>>(scr, Wimg + (size_t)3 * DMODEL * DMODEL, bo, (float*)d_out);
}